// Round 1
// baseline (390.753 us; speedup 1.0000x reference)
//
#include <hip/hip_runtime.h>

#define D 128
#define KNEG 5
#define BLOCK 256
#define SUBS_PER_BLOCK (BLOCK / 32)

// ---- zero the workspace accumulator (harness doesn't re-poison ws between replays)
__global__ void zero_ws_kernel(double* ws) { *ws = 0.0; }

// Stable softplus: log(1+exp(z)) = max(z,0) + log1p(exp(-|z|))
__device__ __forceinline__ float softplus_f(float z) {
    return fmaxf(z, 0.0f) + log1pf(expf(-fabsf(z)));
}

__global__ __launch_bounds__(BLOCK) void neg_loss_main(
    const float* __restrict__ x,
    const int*   __restrict__ ei,    // [2, E] row-major: src at [0..E), dst at [E..2E)
    const int*   __restrict__ nei,   // [K, E] row-major
    double*      __restrict__ ws,
    int E)
{
    const int lane = threadIdx.x & 31;          // lane within 32-lane subgroup
    const int sub  = threadIdx.x >> 5;          // subgroup id within block
    const int gsub = blockIdx.x * SUBS_PER_BLOCK + sub;
    const int nsub = gridDim.x * SUBS_PER_BLOCK;

    float local = 0.0f;

    for (int e = gsub; e < E; e += nsub) {
        const int src = ei[e];
        const int dst = ei[E + e];
        const int n0  = nei[e];
        const int n1  = nei[(size_t)E * 1 + e];
        const int n2  = nei[(size_t)E * 2 + e];
        const int n3  = nei[(size_t)E * 3 + e];
        const int n4  = nei[(size_t)E * 4 + e];

        const int col = lane * 4;
        const float4 vi = *reinterpret_cast<const float4*>(x + (size_t)src * D + col);

        float a0, a1, a2, a3, a4, a5;
        {
            const float4 u = *reinterpret_cast<const float4*>(x + (size_t)dst * D + col);
            a0 = fmaf(vi.x, u.x, fmaf(vi.y, u.y, fmaf(vi.z, u.z, vi.w * u.w)));
        }
        {
            const float4 u = *reinterpret_cast<const float4*>(x + (size_t)n0 * D + col);
            a1 = fmaf(vi.x, u.x, fmaf(vi.y, u.y, fmaf(vi.z, u.z, vi.w * u.w)));
        }
        {
            const float4 u = *reinterpret_cast<const float4*>(x + (size_t)n1 * D + col);
            a2 = fmaf(vi.x, u.x, fmaf(vi.y, u.y, fmaf(vi.z, u.z, vi.w * u.w)));
        }
        {
            const float4 u = *reinterpret_cast<const float4*>(x + (size_t)n2 * D + col);
            a3 = fmaf(vi.x, u.x, fmaf(vi.y, u.y, fmaf(vi.z, u.z, vi.w * u.w)));
        }
        {
            const float4 u = *reinterpret_cast<const float4*>(x + (size_t)n3 * D + col);
            a4 = fmaf(vi.x, u.x, fmaf(vi.y, u.y, fmaf(vi.z, u.z, vi.w * u.w)));
        }
        {
            const float4 u = *reinterpret_cast<const float4*>(x + (size_t)n4 * D + col);
            a5 = fmaf(vi.x, u.x, fmaf(vi.y, u.y, fmaf(vi.z, u.z, vi.w * u.w)));
        }

        // Butterfly reduction within the 32-lane subgroup (xor masks <32 stay
        // inside each 32-lane half of the wave64).
        #pragma unroll
        for (int off = 16; off > 0; off >>= 1) {
            a0 += __shfl_xor(a0, off);
            a1 += __shfl_xor(a1, off);
            a2 += __shfl_xor(a2, off);
            a3 += __shfl_xor(a3, off);
            a4 += __shfl_xor(a4, off);
            a5 += __shfl_xor(a5, off);
        }

        if (lane == 0) {
            // positive: softplus(z) - z = softplus(-z); negatives: softplus(z)
            local += softplus_f(-a0);
            local += softplus_f(a1);
            local += softplus_f(a2);
            local += softplus_f(a3);
            local += softplus_f(a4);
            local += softplus_f(a5);
        }
    }

    __shared__ float sbuf[SUBS_PER_BLOCK];
    if (lane == 0) sbuf[sub] = local;
    __syncthreads();
    if (threadIdx.x == 0) {
        float s = 0.0f;
        #pragma unroll
        for (int i = 0; i < SUBS_PER_BLOCK; ++i) s += sbuf[i];
        atomicAdd(ws, (double)s);
    }
}

__global__ void finalize_kernel(const double* __restrict__ ws,
                                float* __restrict__ out,
                                double count)
{
    *out = (float)(*ws / count);
}

extern "C" void kernel_launch(void* const* d_in, const int* in_sizes, int n_in,
                              void* d_out, int out_size, void* d_ws, size_t ws_size,
                              hipStream_t stream)
{
    const float* x  = (const float*)d_in[0];
    const int*  ei  = (const int*)d_in[1];
    const int*  nei = (const int*)d_in[2];
    const int E = in_sizes[1] / 2;

    double* ws = (double*)d_ws;
    float* out = (float*)d_out;

    zero_ws_kernel<<<dim3(1), dim3(1), 0, stream>>>(ws);

    const int blocks = 2048;   // 8 blocks/CU worth of grid; grid-stride over edges
    neg_loss_main<<<dim3(blocks), dim3(BLOCK), 0, stream>>>(x, ei, nei, ws, E);

    const double count = (double)E * (double)(KNEG + 1);
    finalize_kernel<<<dim3(1), dim3(1), 0, stream>>>(ws, out, count);
}